// Round 12
// baseline (621.206 us; speedup 1.0000x reference)
//
#include <hip/hip_runtime.h>
#include <hip/hip_bf16.h>

#define CCH 64
#define KOFF 27
#define EPSV 1e-5f
#define SLOTS 48   // per-k hit-list capacity (mean ~3, P(>48) ~ 1e-50)

typedef short bf16x8 __attribute__((ext_vector_type(8)));
typedef float f32x4  __attribute__((ext_vector_type(4)));

#define MFMA(a, b, c) __builtin_amdgcn_mfma_f32_16x16x32_bf16((a), (b), (c), 0, 0, 0)

// --- fused pre-pass: blocks [0,54) pack W images; blocks [54,..) stats(x).
// W[k][c][d] fp32 -> fragment-order bf16 image (validated r7/r9/r11):
// elem e: p=e>>3, j=e&7; p=((n*2+half)*4+chunk)*16+col16;
// value = W[k][c=chunk*8+half*32+j][d=n*16+col16]
__global__ __launch_bounds__(256) void k_pre(const float* __restrict__ W1,
                                             const float* __restrict__ W2,
                                             __hip_bfloat16* __restrict__ img1,
                                             __hip_bfloat16* __restrict__ img2,
                                             const float* __restrict__ x, int N,
                                             float* __restrict__ sum,
                                             float* __restrict__ sumsq) {
    if (blockIdx.x < 2 * KOFF) {
        int k = blockIdx.x;
        const float* W = W1; __hip_bfloat16* img = img1;
        if (k >= KOFF) { k -= KOFF; W = W2; img = img2; }
        const float* src = W + (size_t)k * CCH * CCH;
        __hip_bfloat16* dst = img + (size_t)k * CCH * CCH;
        for (int e = threadIdx.x; e < CCH * CCH; e += 256) {
            const int p = e >> 3, j = e & 7;
            const int n = p >> 7, half = (p >> 6) & 1, chunk = (p >> 4) & 3, col = p & 15;
            dst[e] = __float2bfloat16(src[(chunk * 8 + half * 32 + j) * CCH + n * 16 + col]);
        }
        return;
    }
    const int bid = blockIdx.x - 2 * KOFF;
    const int nb  = gridDim.x - 2 * KOFF;
    const int c4  = threadIdx.x & 15;
    const int rg  = threadIdx.x >> 4;
    f32x4 s = {0.f, 0.f, 0.f, 0.f}, s2 = {0.f, 0.f, 0.f, 0.f};
    for (int r = bid * 16 + rg; r < N; r += nb * 16) {
        const float4 v = ((const float4*)x)[(size_t)r * 16 + c4];
        s[0] += v.x; s[1] += v.y; s[2] += v.z; s[3] += v.w;
        s2[0] += v.x * v.x; s2[1] += v.y * v.y; s2[2] += v.z * v.z; s2[3] += v.w * v.w;
    }
    __shared__ float sh[2][16][64];
#pragma unroll
    for (int j = 0; j < 4; ++j) {
        sh[0][rg][c4 * 4 + j] = s[j];
        sh[1][rg][c4 * 4 + j] = s2[j];
    }
    __syncthreads();
    if (threadIdx.x < 128) {
        const int which = threadIdx.x >> 6;
        const int c     = threadIdx.x & 63;
        float a = 0.f;
#pragma unroll
        for (int g = 0; g < 16; ++g) a += sh[which][g][c];
        atomicAdd(which ? &sumsq[c] : &sum[c], a);
    }
}

// ---------------- BN (training stats) + ReLU -> bf16 rows, zero pad row N
__global__ __launch_bounds__(256) void k_bnrelu_bf16(const float* __restrict__ x,
                                                     const float* __restrict__ sum,
                                                     const float* __restrict__ sumsq,
                                                     const float* __restrict__ gamma,
                                                     const float* __restrict__ beta,
                                                     __hip_bfloat16* __restrict__ h,
                                                     int N) {
    const float invN = 1.0f / (float)N;
    const int total = (N + 1) * 8;
    for (int i = blockIdx.x * 256 + threadIdx.x; i < total; i += gridDim.x * 256) {
        const int r  = i >> 3;
        const int c0 = (i & 7) * 8;
        union { __hip_bfloat16 b[8]; int4 v; } pk;
        if (r < N) {
            const float4 va = ((const float4*)x)[i * 2];
            const float4 vb = ((const float4*)x)[i * 2 + 1];
            const float vv[8] = {va.x, va.y, va.z, va.w, vb.x, vb.y, vb.z, vb.w};
#pragma unroll
            for (int j = 0; j < 8; ++j) {
                const int c     = c0 + j;
                const float m   = sum[c] * invN;
                const float var = sumsq[c] * invN - m * m;
                const float sc  = gamma[c] * rsqrtf(var + EPSV);
                const float sh_ = beta[c] - m * sc;
                float t = vv[j] * sc + sh_;
                t = t > 0.0f ? t : 0.0f;
                pk.b[j] = __float2bfloat16(t);
            }
        } else {
            pk.v = make_int4(0, 0, 0, 0);     // zero pad row for kmap misses
        }
        ((int4*)h)[i] = pk.v;
    }
}

// ------------- sparse-compacted MFMA conv, 64 pts/block (4 waves x 16).
// k=13 (identity offset): dense register GEMM, coalesced A.
// k!=13: per-k hit lists built in LDS (hit rate ~4.8%); one compacted
// 16-row fragment per k (padded with zero row N), scatter-add via
// ds_add_f32 into a 16KB LDS out-tile. B read direct-global from the
// fragment-order image (coalesced 1KB/instr, L2-resident). NO W staging,
// NO per-k barriers. Optional fused output stats; optional residual.
__global__ __launch_bounds__(256, 4) void k_conv_sparse(
        const __hip_bfloat16* __restrict__ h, const int* __restrict__ kmap,
        const __hip_bfloat16* __restrict__ Wimg, const float* __restrict__ resid,
        float* __restrict__ out, int N,
        float* __restrict__ stat_sum, float* __restrict__ stat_sq) {
    __shared__ float    otile[64][CCH];        // 16 KB scatter target
    __shared__ unsigned list[KOFF][SLOTS];     // (idx<<6)|r, pad = (N<<6)
    __shared__ int      cnt[KOFF];
    __shared__ float    st[2][CCH];

    const int t = threadIdx.x, lane = t & 63, wave = t >> 6;
    const int col16 = lane & 15, chunk = lane >> 4;
    const int base  = blockIdx.x * 64;

    for (int i = t; i < 64 * CCH; i += 256) ((float*)otile)[i] = 0.f;
    for (int i = t; i < KOFF * SLOTS; i += 256) ((unsigned*)list)[i] = ((unsigned)N << 6);
    if (t < KOFF) cnt[t] = 0;
    if (t < 128) st[t >> 6][t & 63] = 0.f;
    __syncthreads();

    // build per-k hit lists (coalesced kmap slab read); center excluded
    for (int e = t; e < 64 * KOFF; e += 256) {
        const int r = e / KOFF, k = e - r * KOFF;
        if (base + r < N && k != 13) {
            const int idx = kmap[(size_t)base * KOFF + e];
            if (idx != N) {
                const int s = atomicAdd(&cnt[k], 1);
                if (s < SLOTS) list[k][s] = ((unsigned)idx << 6) | (unsigned)r;
            }
        }
    }

    // center (k=13) dense GEMM in registers — overlaps list-build latency
    const int myrow = base + wave * 16 + col16;
    const int cidx  = (myrow < N) ? myrow : N;
    const bf16x8* Ac = (const bf16x8*)(h + (size_t)cidx * CCH) + chunk;
    const bf16x8 cA0 = Ac[0], cA1 = Ac[4];
    const bf16x8* Bc = (const bf16x8*)(Wimg + (size_t)13 * 4096) + lane;
    f32x4 acc[4] = {};
#pragma unroll
    for (int n = 0; n < 4; ++n) {
        const bf16x8 b0 = Bc[(2 * n) * 64], b1 = Bc[(2 * n + 1) * 64];
        acc[n] = MFMA(cA0, b0, acc[n]);
        acc[n] = MFMA(cA1, b1, acc[n]);
    }
    __syncthreads();   // lists complete

    // scattered offsets: wave w handles k = w, w+4, ...
    for (int k = wave; k < KOFF; k += 4) {
        if (k == 13) continue;
        int c = cnt[k];
        if (c <= 0) continue;
        if (c > SLOTS) c = SLOTS;
        const bf16x8* Bk = (const bf16x8*)(Wimg + (size_t)k * 4096) + lane;
        bf16x8 B0[4], B1[4];
#pragma unroll
        for (int n = 0; n < 4; ++n) { B0[n] = Bk[(2 * n) * 64]; B1[n] = Bk[(2 * n + 1) * 64]; }
        for (int s0 = 0; s0 < c; s0 += 16) {           // s0 in {0,16,32}
            const unsigned ent = list[k][s0 + col16];  // pad slots -> zero row N
            const int aidx = (int)(ent >> 6);
            const bf16x8* Ag = (const bf16x8*)(h + (size_t)aidx * CCH) + chunk;
            const bf16x8 a0 = Ag[0], a1 = Ag[4];
            f32x4 p[4] = {};
#pragma unroll
            for (int n = 0; n < 4; ++n) {
                p[n] = MFMA(a0, B0[n], p[n]);
                p[n] = MFMA(a1, B1[n], p[n]);
            }
            // scatter-add: D row i = slot s0+i; lane holds rows chunk*4+j
#pragma unroll
            for (int j = 0; j < 4; ++j) {
                const unsigned e2 = list[k][s0 + chunk * 4 + j];
                const int rr = (int)(e2 & 63);         // pad -> row 0, adds 0.0
#pragma unroll
                for (int n = 0; n < 4; ++n)
                    atomicAdd(&otile[rr][n * 16 + col16], p[n][j]);
            }
        }
    }
    __syncthreads();   // all scatter-adds done

    // epilogue: final = center + otile (+ resid); fused stats
#pragma unroll
    for (int n = 0; n < 4; ++n) {
        const int col = n * 16 + col16;
        float s = 0.f, s2 = 0.f;
#pragma unroll
        for (int j = 0; j < 4; ++j) {
            const int lr  = wave * 16 + chunk * 4 + j;
            const int row = base + lr;
            if (row < N) {
                float v = acc[n][j] + otile[lr][col];
                if (resid) v += resid[(size_t)row * CCH + col];
                out[(size_t)row * CCH + col] = v;
                s += v; s2 += v * v;
            }
        }
        if (stat_sum) {
            atomicAdd(&st[0][col], s);
            atomicAdd(&st[1][col], s2);
        }
    }
    if (stat_sum) {
        __syncthreads();
        if (t < 64)       atomicAdd(&stat_sum[t], st[0][t]);
        else if (t < 128) atomicAdd(&stat_sq[t - 64], st[1][t - 64]);
    }
}

// ---------------------------------------------------------------- launcher
extern "C" void kernel_launch(void* const* d_in, const int* in_sizes, int n_in,
                              void* d_out, int out_size, void* d_ws, size_t ws_size,
                              hipStream_t stream) {
    const float* x      = (const float*)d_in[0];
    const int*   kmap   = (const int*)d_in[1];
    const float* gamma1 = (const float*)d_in[2];
    const float* beta1  = (const float*)d_in[3];
    const float* W1     = (const float*)d_in[4];
    const float* gamma2 = (const float*)d_in[5];
    const float* beta2  = (const float*)d_in[6];
    const float* W2     = (const float*)d_in[7];
    float*       out    = (float*)d_out;

    const int N = in_sizes[0] / CCH;  // 100000

    // ws: stats(1KB) | img1(216KB) | img2(216KB) | hbuf bf16 (N+1)x64
    char* wp = (char*)d_ws;
    float*          stats = (float*)wp;            wp += 1024;
    __hip_bfloat16* img1  = (__hip_bfloat16*)wp;   wp += (size_t)KOFF * CCH * CCH * 2;
    __hip_bfloat16* img2  = (__hip_bfloat16*)wp;   wp += (size_t)KOFF * CCH * CCH * 2;
    __hip_bfloat16* hbuf  = (__hip_bfloat16*)wp;

    hipMemsetAsync(stats, 0, 1024, stream);
    k_pre<<<2 * KOFF + 512, 256, 0, stream>>>(W1, W2, img1, img2, x, N,
                                              stats + 0, stats + 64);

    const int cgrid = (N + 63) / 64;   // 1563

    // block 1: BN1+ReLU -> hbuf; sparse conv(W1) -> d_out (f32 scratch) + BN2 stats
    k_bnrelu_bf16<<<2048, 256, 0, stream>>>(x, stats + 0, stats + 64,
                                            gamma1, beta1, hbuf, N);
    k_conv_sparse<<<cgrid, 256, 0, stream>>>(hbuf, kmap, img1, nullptr, out, N,
                                             stats + 128, stats + 192);

    // block 2: BN2+ReLU -> hbuf; sparse conv(W2) + residual(x) -> d_out
    k_bnrelu_bf16<<<2048, 256, 0, stream>>>(out, stats + 128, stats + 192,
                                            gamma2, beta2, hbuf, N);
    k_conv_sparse<<<cgrid, 256, 0, stream>>>(hbuf, kmap, img2, x, out, N,
                                             nullptr, nullptr);
}